// Round 4
// baseline (482.524 us; speedup 1.0000x reference)
//
#include <hip/hip_runtime.h>

namespace {

constexpr int B = 16, S = 1024, M = 4096, C = 768, D = 256;

typedef __attribute__((ext_vector_type(8))) short bf16x8;
typedef __attribute__((ext_vector_type(4))) float f32x4;

__device__ inline ushort f2bf(float f) {
  uint u = __float_as_uint(f);
  uint r = (u + 0x7FFFu + ((u >> 16) & 1u)) >> 16;
  return (ushort)r;
}

// ---------------------------------------------------------------------------
// Kernel 1: nearest-neighbor argmin (bit-exact reference distance formula).
// float4 LDS staging: 1 ds_read_b128 per candidate instead of 4 ds_read_b32.
// ---------------------------------------------------------------------------
__global__ __launch_bounds__(256)
void nn_kernel(const float* __restrict__ xyz, const float* __restrict__ p,
               int* __restrict__ idx_out) {
  const int b = blockIdx.y;
  const int t = threadIdx.x;
  const int seed = blockIdx.x * 16 + (t >> 4);
  const int l16 = t & 15;

  const float sx = xyz[((size_t)b * S + seed) * 3 + 0];
  const float sy = xyz[((size_t)b * S + seed) * 3 + 1];
  const float sz = xyz[((size_t)b * S + seed) * 3 + 2];
  const float ss = __fadd_rn(__fadd_rn(__fmul_rn(sx, sx), __fmul_rn(sy, sy)),
                             __fmul_rn(sz, sz));

  __shared__ float4 pt[256];

  float best = 3.4028235e38f;
  int besti = 0;
  const float* pb = p + (size_t)b * M * 3;

  for (int m0 = 0; m0 < M; m0 += 256) {
    __syncthreads();
    {
      const float a0 = pb[(size_t)(m0 + t) * 3 + 0];
      const float a1 = pb[(size_t)(m0 + t) * 3 + 1];
      const float a2 = pb[(size_t)(m0 + t) * 3 + 2];
      const float pp = __fadd_rn(__fadd_rn(__fmul_rn(a0, a0), __fmul_rn(a1, a1)),
                                 __fmul_rn(a2, a2));
      pt[t] = make_float4(a0, a1, a2, pp);
    }
    __syncthreads();
    #pragma unroll 4
    for (int j = l16; j < 256; j += 16) {
      const float4 q = pt[j];
      float dot = __fmul_rn(sx, q.x);
      dot = __fadd_rn(dot, __fmul_rn(sy, q.y));
      dot = __fadd_rn(dot, __fmul_rn(sz, q.z));
      const float d2 = __fadd_rn(__fsub_rn(ss, __fmul_rn(2.0f, dot)), q.w);
      const int mi = m0 + j;
      if (d2 < best || (d2 == best && mi < besti)) { best = d2; besti = mi; }
    }
  }
  #pragma unroll
  for (int off = 8; off >= 1; off >>= 1) {
    const float ob = __shfl_xor(best, off, 16);
    const int   oi = __shfl_xor(besti, off, 16);
    if (ob < best || (ob == best && oi < besti)) { best = ob; besti = oi; }
  }
  if (l16 == 0) idx_out[b * S + seed] = besti;
}

// ---------------------------------------------------------------------------
// Kernel 1b: per-batch counting sort by bucket (m>>4). A bucket is exactly one
// 64B line of f_last per channel, so within-bucket order is irrelevant.
// ---------------------------------------------------------------------------
__global__ __launch_bounds__(256)
void bucket_sort_kernel(const int* __restrict__ idx, int* __restrict__ sIdx,
                        int* __restrict__ sS) {
  const int b = blockIdx.x;
  const int t = threadIdx.x;
  __shared__ int keys[1024];
  __shared__ int cnt[256];
  __shared__ int base[256];
  __shared__ int wsum[4];

  cnt[t] = 0;
  #pragma unroll
  for (int i = 0; i < 4; ++i) keys[t + 256 * i] = idx[b * S + t + 256 * i];
  __syncthreads();
  #pragma unroll
  for (int i = 0; i < 4; ++i) atomicAdd(&cnt[keys[t + 256 * i] >> 4], 1);
  __syncthreads();

  const int v = cnt[t];
  int sc = v;
  #pragma unroll
  for (int off = 1; off < 64; off <<= 1) {
    const int o = __shfl_up(sc, off);
    if ((t & 63) >= off) sc += o;
  }
  if ((t & 63) == 63) wsum[t >> 6] = sc;
  __syncthreads();
  int wb = 0;
  #pragma unroll
  for (int w = 0; w < 4; ++w)
    if (w < (t >> 6)) wb += wsum[w];
  base[t] = wb + sc - v;   // exclusive prefix over all 256 buckets
  cnt[t] = 0;              // reuse as intra-bucket offset counter
  __syncthreads();

  #pragma unroll
  for (int i = 0; i < 4; ++i) {
    const int s = t + 256 * i;
    const int m = keys[s];
    const int bu = m >> 4;
    const int r = base[bu] + atomicAdd(&cnt[bu], 1);
    sIdx[b * S + r] = m;
    sS[b * S + r] = s;
  }
}

// ---------------------------------------------------------------------------
// Kernel 2: gather + LayerNorm, FOUR consecutive sorted ranks per block.
// Consecutive ranks share the same m-bucket (= same 64B line per channel),
// so ranks 2..4 hit L1; 12 independent loads in flight per thread.
// XCD-aware swizzle over rank-quads. Output bf16 [B][S][C].
// ---------------------------------------------------------------------------
__global__ __launch_bounds__(256)
void gather_ln_kernel(const float* __restrict__ f, const int* __restrict__ sIdx,
                      const int* __restrict__ sS,
                      const float* __restrict__ gamma, const float* __restrict__ beta,
                      ushort* __restrict__ xln) {
  const int b = blockIdx.y;
  const int rl = blockIdx.x;                         // 0..255
  const int r0 = (((rl & 7) << 5) + (rl >> 3)) << 2; // XCD-contiguous quad rank
  const int t = threadIdx.x;

  int sR[4], mR[4];
  #pragma unroll
  for (int i = 0; i < 4; ++i) {
    sR[i] = sS[b * S + r0 + i];
    mR[i] = sIdx[b * S + r0 + i];
  }

  const float* fb = f + (size_t)b * C * M;
  float v[4][3];
  #pragma unroll
  for (int i = 0; i < 4; ++i) {
    v[i][0] = fb[(size_t)(t      ) * M + mR[i]];
    v[i][1] = fb[(size_t)(t + 256) * M + mR[i]];
    v[i][2] = fb[(size_t)(t + 512) * M + mR[i]];
  }

  const float g0 = gamma[t], g1 = gamma[t + 256], g2 = gamma[t + 512];
  const float e0 = beta[t],  e1 = beta[t + 256],  e2 = beta[t + 512];

  __shared__ float red[4][4];   // [rank][wave]
  __shared__ float stats[8];    // 0..3 mu, 4..7 rsigma
  const int wave = t >> 6;

  float ps[4];
  #pragma unroll
  for (int i = 0; i < 4; ++i) ps[i] = v[i][0] + v[i][1] + v[i][2];
  #pragma unroll
  for (int off = 32; off >= 1; off >>= 1) {
    #pragma unroll
    for (int i = 0; i < 4; ++i) ps[i] += __shfl_xor(ps[i], off);
  }
  if ((t & 63) == 0) {
    #pragma unroll
    for (int i = 0; i < 4; ++i) red[i][wave] = ps[i];
  }
  __syncthreads();
  if (t < 4)
    stats[t] = (red[t][0] + red[t][1] + red[t][2] + red[t][3]) * (1.0f / 768.0f);
  __syncthreads();

  float d[4][3];
  #pragma unroll
  for (int i = 0; i < 4; ++i) {
    const float mu = stats[i];
    d[i][0] = v[i][0] - mu; d[i][1] = v[i][1] - mu; d[i][2] = v[i][2] - mu;
  }
  float pv[4];
  #pragma unroll
  for (int i = 0; i < 4; ++i)
    pv[i] = d[i][0] * d[i][0] + d[i][1] * d[i][1] + d[i][2] * d[i][2];
  #pragma unroll
  for (int off = 32; off >= 1; off >>= 1) {
    #pragma unroll
    for (int i = 0; i < 4; ++i) pv[i] += __shfl_xor(pv[i], off);
  }
  if ((t & 63) == 0) {
    #pragma unroll
    for (int i = 0; i < 4; ++i) red[i][wave] = pv[i];
  }
  __syncthreads();
  if (t < 4) {
    const float var = (red[t][0] + red[t][1] + red[t][2] + red[t][3]) * (1.0f / 768.0f);
    stats[4 + t] = 1.0f / sqrtf(var + 1e-5f);
  }
  __syncthreads();

  #pragma unroll
  for (int i = 0; i < 4; ++i) {
    const float rs = stats[4 + i];
    ushort* o = xln + ((size_t)b * S + sR[i]) * C;
    o[t      ] = f2bf((d[i][0] * rs) * g0 + e0);
    o[t + 256] = f2bf((d[i][1] * rs) * g1 + e1);
    o[t + 512] = f2bf((d[i][2] * rs) * g2 + e2);
  }
}

// ---------------------------------------------------------------------------
// Kernel 3 (merged): flat grid.
//   bid <  1024 : transpose+convert seed_features [B][D][S] f32 -> fused[...,0:256]
//   bid >= 1024 : convert the three weight matrices f32 -> bf16
// ---------------------------------------------------------------------------
__global__ __launch_bounds__(256)
void prep_kernel(const float* __restrict__ sf, ushort* __restrict__ fused,
                 const float* __restrict__ w0, int n0, ushort* __restrict__ o0,
                 const float* __restrict__ w1, int n1, ushort* __restrict__ o1,
                 const float* __restrict__ w2, int n2, ushort* __restrict__ o2) {
  __shared__ float tile[64][68];
  const int bid = blockIdx.x;
  const int t = threadIdx.x;

  if (bid < 1024) {
    const int b  = bid >> 6;
    const int d0 = ((bid >> 4) & 3) * 64;
    const int s0 = (bid & 15) * 64;

    const float* inb = sf + ((size_t)b * D + d0) * S + s0;
    #pragma unroll
    for (int q = 0; q < 4; ++q) {
      const int rr = (t >> 4) + q * 16;
      const int c4 = (t & 15) * 4;
      const float4 v = *(const float4*)&inb[(size_t)rr * S + c4];
      *(float4*)&tile[rr][c4] = v;
    }
    __syncthreads();
    #pragma unroll
    for (int q = 0; q < 4; ++q) {
      const int srow = (t >> 4) + q * 16;
      const int dc = (t & 15) * 4;
      ushort4 o;
      o.x = f2bf(tile[dc + 0][srow]);
      o.y = f2bf(tile[dc + 1][srow]);
      o.z = f2bf(tile[dc + 2][srow]);
      o.w = f2bf(tile[dc + 3][srow]);
      *(ushort4*)&fused[((size_t)b * S + s0 + srow) * 512 + d0 + dc] = o;
    }
  } else {
    const int id = bid - 1024;          // 0..767
    const int which = id >> 8;
    const float* src = which == 0 ? w0 : which == 1 ? w1 : w2;
    ushort* dst = which == 0 ? o0 : which == 1 ? o1 : o2;
    const int n = which == 0 ? n0 : which == 1 ? n1 : n2;
    const int i = ((id & 255) * 256 + t) * 4;
    if (i < n) {
      const float4 v = *(const float4*)&src[i];
      ushort4 o;
      o.x = f2bf(v.x); o.y = f2bf(v.y); o.z = f2bf(v.z); o.w = f2bf(v.w);
      *(ushort4*)&dst[i] = o;
    }
  }
}

// ---------------------------------------------------------------------------
// Kernel 5: bf16 MFMA GEMM.  out[b,o,s] = act( sum_k W[o,k] X[b,s,k] + bias[o] )
// W: bf16 [O][K] (k contiguous).  X: bf16 [B][S][K] (k contiguous).
// Tile 256o x 64s (halves X re-reads vs 128x128; LDS 26.6 KB single-buffered
// -> more blocks/CU).  Block: 256 thr / 4 waves; wave w owns s-range
// [w*16, w*16+16), all 256 o.  Register prefetch of the next K-step.
// outMode 0: bf16 [B][S][ldOut] at column colOff (+optional ReLU)
// outMode 1: fp32 [B][O][S] (final output)
// ---------------------------------------------------------------------------
__global__ __launch_bounds__(256)
void gemm_bf16_kernel(const ushort* __restrict__ W, int K, int O,
                      const ushort* __restrict__ X,
                      const float* __restrict__ bias,
                      void* __restrict__ out, int outMode, int ldOut, int colOff,
                      int relu) {
  const int b  = blockIdx.z;
  const int s0 = blockIdx.x * 64;
  const int o0 = blockIdx.y * 256;
  const int t  = threadIdx.x;
  const int wave = t >> 6;
  const int lane = t & 63;
  const int l16 = lane & 15;
  const int quad = lane >> 4;

  // 80-byte row stride (40 ushorts): 16B-aligned rows, benign bank aliasing
  __shared__ ushort Wt[256 * 40];
  __shared__ ushort Xt[64 * 40];
  __shared__ float biasS[256];

  biasS[t] = bias[o0 + t];

  f32x4 acc[16];
  const f32x4 z = {0.f, 0.f, 0.f, 0.f};
  #pragma unroll
  for (int of = 0; of < 16; ++of) acc[of] = z;

  const ushort* Xb = X + (size_t)b * S * K;
  const int kg = t & 3;        // k-group: 8 bf16 each
  const int row = t >> 2;      // 0..63
  const size_t wBase = (size_t)(o0 + row) * K + kg * 8;
  const size_t xBase = (size_t)(s0 + row) * K + kg * 8;

  // prologue: load K-step 0 into registers (4 W quadrants + 1 X)
  uint4 wv[4], xv;
  #pragma unroll
  for (int q = 0; q < 4; ++q)
    wv[q] = *(const uint4*)&W[wBase + (size_t)(64 * q) * K];
  xv = *(const uint4*)&Xb[xBase];

  for (int c0 = 0; c0 < K; c0 += 32) {
    __syncthreads();
    #pragma unroll
    for (int q = 0; q < 4; ++q)
      *(uint4*)&Wt[(row + 64 * q) * 40 + kg * 8] = wv[q];
    *(uint4*)&Xt[row * 40 + kg * 8] = xv;
    __syncthreads();

    if (c0 + 32 < K) {   // issue next step's loads; consumed next iteration
      #pragma unroll
      for (int q = 0; q < 4; ++q)
        wv[q] = *(const uint4*)&W[wBase + (size_t)(64 * q) * K + c0 + 32];
      xv = *(const uint4*)&Xb[xBase + c0 + 32];
    }

    const bf16x8 bfr = *(const bf16x8*)&Xt[(wave * 16 + l16) * 40 + quad * 8];
    #pragma unroll
    for (int of = 0; of < 16; ++of) {
      const bf16x8 afr = *(const bf16x8*)&Wt[(of * 16 + l16) * 40 + quad * 8];
      acc[of] = __builtin_amdgcn_mfma_f32_16x16x32_bf16(afr, bfr, acc[of], 0, 0, 0);
    }
  }

  // epilogue: lane holds D[o = of*16 + quad*4 + r][s = wave*16 + l16]
  const int s = s0 + wave * 16 + l16;
  if (outMode == 0) {
    ushort* ob = (ushort*)out;
    #pragma unroll
    for (int of = 0; of < 16; ++of) {
      const int ol = of * 16 + quad * 4;
      float v0 = acc[of].x + biasS[ol + 0];
      float v1 = acc[of].y + biasS[ol + 1];
      float v2 = acc[of].z + biasS[ol + 2];
      float v3 = acc[of].w + biasS[ol + 3];
      if (relu) {
        v0 = fmaxf(v0, 0.f); v1 = fmaxf(v1, 0.f);
        v2 = fmaxf(v2, 0.f); v3 = fmaxf(v3, 0.f);
      }
      ushort4 st;
      st.x = f2bf(v0); st.y = f2bf(v1); st.z = f2bf(v2); st.w = f2bf(v3);
      *(ushort4*)&ob[((size_t)b * S + s) * ldOut + colOff + o0 + ol] = st;
    }
  } else {
    float* o32 = (float*)out;
    #pragma unroll
    for (int of = 0; of < 16; ++of) {
      const int ol = of * 16 + quad * 4;
      const float vr[4] = {acc[of].x, acc[of].y, acc[of].z, acc[of].w};
      #pragma unroll
      for (int r = 0; r < 4; ++r) {
        const int o = o0 + ol + r;
        o32[((size_t)b * O + o) * S + s] = vr[r] + biasS[ol + r];
      }
    }
  }
}

}  // namespace

extern "C" void kernel_launch(void* const* d_in, const int* in_sizes, int n_in,
                              void* d_out, int out_size, void* d_ws, size_t ws_size,
                              hipStream_t stream) {
  const float* seed_xyz  = (const float*)d_in[0];   // [B,S,3]
  const float* p_last    = (const float*)d_in[1];   // [B,M,3]
  const float* f_last    = (const float*)d_in[2];   // [B,C,M]
  const float* seed_feat = (const float*)d_in[3];   // [B,D,S]
  const float* ln_gamma  = (const float*)d_in[4];   // [C]
  const float* ln_beta   = (const float*)d_in[5];   // [C]
  const float* proj_w    = (const float*)d_in[6];   // [D,C]
  const float* proj_b    = (const float*)d_in[7];   // [D]
  const float* mlp_w1    = (const float*)d_in[8];   // [512,512]
  const float* mlp_b1    = (const float*)d_in[9];   // [512]
  const float* mlp_w2    = (const float*)d_in[10];  // [256,512]
  const float* mlp_b2    = (const float*)d_in[11];  // [256]
  float* out = (float*)d_out;                       // [B,256,S] fp32

  // workspace layout:
  //   0      +64KB   idx [B*S] int
  //   64KB   +64KB   sortedIdx
  //   128KB  +64KB   sortedS
  //   256KB  +384KB  proj_w bf16 [256][768]
  //   640KB  +512KB  mlp_w1 bf16 [512][512]
  //   1152KB +256KB  mlp_w2 bf16 [256][512]
  //   2MB    +24MB   xln   bf16 [B][S][768]
  //   26MB   +16MB   fused bf16 [B][S][512]  (0:256 seed_feat^T, 256:512 proj)
  //   42MB   +16MB   h     bf16 [B][S][512]
  char* ws = (char*)d_ws;
  int*    idx   = (int*)(ws);
  int*    sIdx  = (int*)(ws + (64 << 10));
  int*    sS    = (int*)(ws + (128 << 10));
  ushort* wp_bf = (ushort*)(ws + (256 << 10));
  ushort* w1_bf = (ushort*)(ws + (640 << 10));
  ushort* w2_bf = (ushort*)(ws + (1152 << 10));
  ushort* xln   = (ushort*)(ws + (2ull << 20));
  ushort* fused = (ushort*)(ws + (26ull << 20));
  ushort* hbuf  = (ushort*)(ws + (42ull << 20));

  // 1) nearest neighbor + bucket sort by idx
  nn_kernel<<<dim3(S / 16, B), 256, 0, stream>>>(seed_xyz, p_last, idx);
  bucket_sort_kernel<<<dim3(B), 256, 0, stream>>>(idx, sIdx, sS);

  // 2) gather + layernorm -> xln bf16 [B][S][768]  (4 ranks per block)
  gather_ln_kernel<<<dim3(S / 4, B), 256, 0, stream>>>(f_last, sIdx, sS,
                                                       ln_gamma, ln_beta, xln);

  // 3) seed_features -> fused[:, :, 0:256] bf16 ; weights -> bf16 (one kernel)
  prep_kernel<<<dim3(1024 + 768), 256, 0, stream>>>(
      seed_feat, fused,
      proj_w, D * C, wp_bf, mlp_w1, 512 * 512, w1_bf, mlp_w2, 256 * 512, w2_bf);

  // 4) proj = relu(proj_w @ xln + b) -> fused[:, :, 256:512]
  gemm_bf16_kernel<<<dim3(S / 64, 256 / 256, B), 256, 0, stream>>>(
      wp_bf, C, 256, xln, proj_b, fused, 0, 512, 256, 1);

  // 5) h = relu(mlp_w1 @ fused + b1) -> hbuf [B][S][512]
  gemm_bf16_kernel<<<dim3(S / 64, 512 / 256, B), 256, 0, stream>>>(
      w1_bf, 512, 512, fused, mlp_b1, hbuf, 0, 512, 0, 1);

  // 6) out = mlp_w2 @ h + b2 -> fp32 [B][256][S]
  gemm_bf16_kernel<<<dim3(S / 64, 256 / 256, B), 256, 0, stream>>>(
      w2_bf, 512, 256, hbuf, mlp_b2, out, 1, 0, 0, 0);
}

// Round 5
// 415.155 us; speedup vs baseline: 1.1623x; 1.1623x over previous
//
#include <hip/hip_runtime.h>

namespace {

constexpr int B = 16, S = 1024, M = 4096, C = 768, D = 256;

typedef __attribute__((ext_vector_type(8))) short bf16x8;
typedef __attribute__((ext_vector_type(4))) float f32x4;

__device__ inline ushort f2bf(float f) {
  uint u = __float_as_uint(f);
  uint r = (u + 0x7FFFu + ((u >> 16) & 1u)) >> 16;
  return (ushort)r;
}

// ---------------------------------------------------------------------------
// Kernel 1: nearest-neighbor argmin (bit-exact reference distance formula).
// 4 seeds per lane: each candidate float4 LDS read is amortized over 4
// distance evals (LDS-issue was the bound: ~20us -> ~5us on the ds pipe).
// ---------------------------------------------------------------------------
__global__ __launch_bounds__(256)
void nn_kernel(const float* __restrict__ xyz, const float* __restrict__ p,
               int* __restrict__ idx_out) {
  const int b = blockIdx.y;
  const int t = threadIdx.x;
  const int l16 = t & 15;
  const int seed0 = blockIdx.x * 64 + (t >> 4) * 4;

  float sx[4], sy[4], sz[4], ss[4];
  #pragma unroll
  for (int k = 0; k < 4; ++k) {
    const float x = xyz[((size_t)b * S + seed0 + k) * 3 + 0];
    const float y = xyz[((size_t)b * S + seed0 + k) * 3 + 1];
    const float z = xyz[((size_t)b * S + seed0 + k) * 3 + 2];
    sx[k] = x; sy[k] = y; sz[k] = z;
    ss[k] = __fadd_rn(__fadd_rn(__fmul_rn(x, x), __fmul_rn(y, y)),
                      __fmul_rn(z, z));
  }

  __shared__ float4 pt[256];

  float best[4];
  int besti[4];
  #pragma unroll
  for (int k = 0; k < 4; ++k) { best[k] = 3.4028235e38f; besti[k] = 0; }

  const float* pb = p + (size_t)b * M * 3;

  for (int m0 = 0; m0 < M; m0 += 256) {
    __syncthreads();
    {
      const float a0 = pb[(size_t)(m0 + t) * 3 + 0];
      const float a1 = pb[(size_t)(m0 + t) * 3 + 1];
      const float a2 = pb[(size_t)(m0 + t) * 3 + 2];
      const float pp = __fadd_rn(__fadd_rn(__fmul_rn(a0, a0), __fmul_rn(a1, a1)),
                                 __fmul_rn(a2, a2));
      pt[t] = make_float4(a0, a1, a2, pp);
    }
    __syncthreads();
    #pragma unroll 2
    for (int j = l16; j < 256; j += 16) {
      const float4 q = pt[j];
      const int mi = m0 + j;
      #pragma unroll
      for (int k = 0; k < 4; ++k) {
        float dot = __fmul_rn(sx[k], q.x);
        dot = __fadd_rn(dot, __fmul_rn(sy[k], q.y));
        dot = __fadd_rn(dot, __fmul_rn(sz[k], q.z));
        const float d2 = __fadd_rn(__fsub_rn(ss[k], __fmul_rn(2.0f, dot)), q.w);
        if (d2 < best[k] || (d2 == best[k] && mi < besti[k])) {
          best[k] = d2; besti[k] = mi;
        }
      }
    }
  }
  #pragma unroll
  for (int k = 0; k < 4; ++k) {
    float bk = best[k]; int ik = besti[k];
    #pragma unroll
    for (int off = 8; off >= 1; off >>= 1) {
      const float ob = __shfl_xor(bk, off, 16);
      const int   oi = __shfl_xor(ik, off, 16);
      if (ob < bk || (ob == bk && oi < ik)) { bk = ob; ik = oi; }
    }
    if (l16 == 0) idx_out[b * S + seed0 + k] = ik;
  }
}

// ---------------------------------------------------------------------------
// Kernel 1b: per-batch counting sort by bucket (m>>4). A bucket is exactly one
// 64B line of f_last per channel, so within-bucket order is irrelevant.
// ---------------------------------------------------------------------------
__global__ __launch_bounds__(256)
void bucket_sort_kernel(const int* __restrict__ idx, int* __restrict__ sIdx,
                        int* __restrict__ sS) {
  const int b = blockIdx.x;
  const int t = threadIdx.x;
  __shared__ int keys[1024];
  __shared__ int cnt[256];
  __shared__ int base[256];
  __shared__ int wsum[4];

  cnt[t] = 0;
  #pragma unroll
  for (int i = 0; i < 4; ++i) keys[t + 256 * i] = idx[b * S + t + 256 * i];
  __syncthreads();
  #pragma unroll
  for (int i = 0; i < 4; ++i) atomicAdd(&cnt[keys[t + 256 * i] >> 4], 1);
  __syncthreads();

  const int v = cnt[t];
  int sc = v;
  #pragma unroll
  for (int off = 1; off < 64; off <<= 1) {
    const int o = __shfl_up(sc, off);
    if ((t & 63) >= off) sc += o;
  }
  if ((t & 63) == 63) wsum[t >> 6] = sc;
  __syncthreads();
  int wb = 0;
  #pragma unroll
  for (int w = 0; w < 4; ++w)
    if (w < (t >> 6)) wb += wsum[w];
  base[t] = wb + sc - v;   // exclusive prefix over all 256 buckets
  cnt[t] = 0;              // reuse as intra-bucket offset counter
  __syncthreads();

  #pragma unroll
  for (int i = 0; i < 4; ++i) {
    const int s = t + 256 * i;
    const int m = keys[s];
    const int bu = m >> 4;
    const int r = base[bu] + atomicAdd(&cnt[bu], 1);
    sIdx[b * S + r] = m;
    sS[b * S + r] = s;
  }
}

// ---------------------------------------------------------------------------
// Kernel 2: gather + LayerNorm, FOUR consecutive sorted ranks per block.
// Consecutive ranks share the same m-bucket (= same 64B line per channel),
// so ranks 2..4 hit L1; 12 independent loads in flight per thread.
// XCD-aware swizzle over rank-quads. Output bf16 [B][S][C].
// ---------------------------------------------------------------------------
__global__ __launch_bounds__(256)
void gather_ln_kernel(const float* __restrict__ f, const int* __restrict__ sIdx,
                      const int* __restrict__ sS,
                      const float* __restrict__ gamma, const float* __restrict__ beta,
                      ushort* __restrict__ xln) {
  const int b = blockIdx.y;
  const int rl = blockIdx.x;                         // 0..255
  const int r0 = (((rl & 7) << 5) + (rl >> 3)) << 2; // XCD-contiguous quad rank
  const int t = threadIdx.x;

  int sR[4], mR[4];
  #pragma unroll
  for (int i = 0; i < 4; ++i) {
    sR[i] = sS[b * S + r0 + i];
    mR[i] = sIdx[b * S + r0 + i];
  }

  const float* fb = f + (size_t)b * C * M;
  float v[4][3];
  #pragma unroll
  for (int i = 0; i < 4; ++i) {
    v[i][0] = fb[(size_t)(t      ) * M + mR[i]];
    v[i][1] = fb[(size_t)(t + 256) * M + mR[i]];
    v[i][2] = fb[(size_t)(t + 512) * M + mR[i]];
  }

  const float g0 = gamma[t], g1 = gamma[t + 256], g2 = gamma[t + 512];
  const float e0 = beta[t],  e1 = beta[t + 256],  e2 = beta[t + 512];

  __shared__ float red[4][4];   // [rank][wave]
  __shared__ float stats[8];    // 0..3 mu, 4..7 rsigma
  const int wave = t >> 6;

  float ps[4];
  #pragma unroll
  for (int i = 0; i < 4; ++i) ps[i] = v[i][0] + v[i][1] + v[i][2];
  #pragma unroll
  for (int off = 32; off >= 1; off >>= 1) {
    #pragma unroll
    for (int i = 0; i < 4; ++i) ps[i] += __shfl_xor(ps[i], off);
  }
  if ((t & 63) == 0) {
    #pragma unroll
    for (int i = 0; i < 4; ++i) red[i][wave] = ps[i];
  }
  __syncthreads();
  if (t < 4)
    stats[t] = (red[t][0] + red[t][1] + red[t][2] + red[t][3]) * (1.0f / 768.0f);
  __syncthreads();

  float d[4][3];
  #pragma unroll
  for (int i = 0; i < 4; ++i) {
    const float mu = stats[i];
    d[i][0] = v[i][0] - mu; d[i][1] = v[i][1] - mu; d[i][2] = v[i][2] - mu;
  }
  float pv[4];
  #pragma unroll
  for (int i = 0; i < 4; ++i)
    pv[i] = d[i][0] * d[i][0] + d[i][1] * d[i][1] + d[i][2] * d[i][2];
  #pragma unroll
  for (int off = 32; off >= 1; off >>= 1) {
    #pragma unroll
    for (int i = 0; i < 4; ++i) pv[i] += __shfl_xor(pv[i], off);
  }
  if ((t & 63) == 0) {
    #pragma unroll
    for (int i = 0; i < 4; ++i) red[i][wave] = pv[i];
  }
  __syncthreads();
  if (t < 4) {
    const float var = (red[t][0] + red[t][1] + red[t][2] + red[t][3]) * (1.0f / 768.0f);
    stats[4 + t] = 1.0f / sqrtf(var + 1e-5f);
  }
  __syncthreads();

  #pragma unroll
  for (int i = 0; i < 4; ++i) {
    const float rs = stats[4 + i];
    ushort* o = xln + ((size_t)b * S + sR[i]) * C;
    o[t      ] = f2bf((d[i][0] * rs) * g0 + e0);
    o[t + 256] = f2bf((d[i][1] * rs) * g1 + e1);
    o[t + 512] = f2bf((d[i][2] * rs) * g2 + e2);
  }
}

// ---------------------------------------------------------------------------
// Kernel 3 (merged): flat grid.
//   bid <  1024 : transpose+convert seed_features [B][D][S] f32 -> fused[...,0:256]
//   bid >= 1024 : convert the three weight matrices f32 -> bf16
// ---------------------------------------------------------------------------
__global__ __launch_bounds__(256)
void prep_kernel(const float* __restrict__ sf, ushort* __restrict__ fused,
                 const float* __restrict__ w0, int n0, ushort* __restrict__ o0,
                 const float* __restrict__ w1, int n1, ushort* __restrict__ o1,
                 const float* __restrict__ w2, int n2, ushort* __restrict__ o2) {
  __shared__ float tile[64][68];
  const int bid = blockIdx.x;
  const int t = threadIdx.x;

  if (bid < 1024) {
    const int b  = bid >> 6;
    const int d0 = ((bid >> 4) & 3) * 64;
    const int s0 = (bid & 15) * 64;

    const float* inb = sf + ((size_t)b * D + d0) * S + s0;
    #pragma unroll
    for (int q = 0; q < 4; ++q) {
      const int rr = (t >> 4) + q * 16;
      const int c4 = (t & 15) * 4;
      const float4 v = *(const float4*)&inb[(size_t)rr * S + c4];
      *(float4*)&tile[rr][c4] = v;
    }
    __syncthreads();
    #pragma unroll
    for (int q = 0; q < 4; ++q) {
      const int srow = (t >> 4) + q * 16;
      const int dc = (t & 15) * 4;
      ushort4 o;
      o.x = f2bf(tile[dc + 0][srow]);
      o.y = f2bf(tile[dc + 1][srow]);
      o.z = f2bf(tile[dc + 2][srow]);
      o.w = f2bf(tile[dc + 3][srow]);
      *(ushort4*)&fused[((size_t)b * S + s0 + srow) * 512 + d0 + dc] = o;
    }
  } else {
    const int id = bid - 1024;          // 0..767
    const int which = id >> 8;
    const float* src = which == 0 ? w0 : which == 1 ? w1 : w2;
    ushort* dst = which == 0 ? o0 : which == 1 ? o1 : o2;
    const int n = which == 0 ? n0 : which == 1 ? n1 : n2;
    const int i = ((id & 255) * 256 + t) * 4;
    if (i < n) {
      const float4 v = *(const float4*)&src[i];
      ushort4 o;
      o.x = f2bf(v.x); o.y = f2bf(v.y); o.z = f2bf(v.z); o.w = f2bf(v.w);
      *(ushort4*)&dst[i] = o;
    }
  }
}

// ---------------------------------------------------------------------------
// Kernel 5: bf16 MFMA GEMM (Round-3 verified structure, 409.1us total).
// out[b,o,s] = act( sum_k W[o,k] X[b,s,k] + bias[o] )
// W: bf16 [O][K] (k contiguous).  X: bf16 [B][S][K] (k contiguous).
// Block: 256 thr (4 waves), tile 128o x 128s; wave w: s-range [w*32, w*32+32).
// Double-buffered LDS, ONE barrier per K-step, 2-step global prefetch.
// outMode 0: bf16 [B][S][ldOut] at column colOff (+optional ReLU)
// outMode 1: fp32 [B][O][S] (final output)
// ---------------------------------------------------------------------------
__global__ __launch_bounds__(256)
void gemm_bf16_kernel(const ushort* __restrict__ W, int K, int O,
                      const ushort* __restrict__ X,
                      const float* __restrict__ bias,
                      void* __restrict__ out, int outMode, int ldOut, int colOff,
                      int relu) {
  const int b  = blockIdx.z;
  const int s0 = blockIdx.x * 128;
  const int o0 = blockIdx.y * 128;
  const int t  = threadIdx.x;
  const int wave = t >> 6;
  const int lane = t & 63;
  const int l16 = lane & 15;
  const int quad = lane >> 4;

  // 80-byte row stride (40 ushorts): 16B-aligned rows, 2-way bank alias (free)
  __shared__ ushort Wt[2][128 * 40];
  __shared__ ushort Xt[2][128 * 40];
  __shared__ float biasS[128];

  if (t < 128) biasS[t] = bias[o0 + t];

  f32x4 acc[8][2];
  const f32x4 z = {0.f, 0.f, 0.f, 0.f};
  #pragma unroll
  for (int of = 0; of < 8; ++of) { acc[of][0] = z; acc[of][1] = z; }

  const ushort* Xb = X + (size_t)b * S * K;
  const int kg = t & 3;        // k-group: 8 bf16 each
  const int row = t >> 2;      // 0..63
  const size_t wBase = (size_t)(o0 + row) * K + kg * 8;
  const size_t xBase = (size_t)(s0 + row) * K + kg * 8;
  const size_t wBase2 = wBase + (size_t)64 * K;
  const size_t xBase2 = xBase + (size_t)64 * K;
  const int T = K >> 5;        // K/32 tiles

  // prologue: tile 0 -> LDS buf0; tile 1 -> regs
  uint4 wv0 = *(const uint4*)&W[wBase];
  uint4 wv1 = *(const uint4*)&W[wBase2];
  uint4 xv0 = *(const uint4*)&Xb[xBase];
  uint4 xv1 = *(const uint4*)&Xb[xBase2];
  *(uint4*)&Wt[0][row * 40 + kg * 8] = wv0;
  *(uint4*)&Wt[0][(row + 64) * 40 + kg * 8] = wv1;
  *(uint4*)&Xt[0][row * 40 + kg * 8] = xv0;
  *(uint4*)&Xt[0][(row + 64) * 40 + kg * 8] = xv1;
  if (T > 1) {
    wv0 = *(const uint4*)&W[wBase + 32];
    wv1 = *(const uint4*)&W[wBase2 + 32];
    xv0 = *(const uint4*)&Xb[xBase + 32];
    xv1 = *(const uint4*)&Xb[xBase2 + 32];
  }
  __syncthreads();   // buf0 visible

  for (int tt = 0; tt < T; ++tt) {
    const int cur = tt & 1;

    // (A) stage tile tt+1 (in regs) into the other buffer
    if (tt + 1 < T) {
      *(uint4*)&Wt[cur ^ 1][row * 40 + kg * 8] = wv0;
      *(uint4*)&Wt[cur ^ 1][(row + 64) * 40 + kg * 8] = wv1;
      *(uint4*)&Xt[cur ^ 1][row * 40 + kg * 8] = xv0;
      *(uint4*)&Xt[cur ^ 1][(row + 64) * 40 + kg * 8] = xv1;
    }
    // (B) issue tile tt+2 global loads
    if (tt + 2 < T) {
      const int c = (tt + 2) * 32;
      wv0 = *(const uint4*)&W[wBase + c];
      wv1 = *(const uint4*)&W[wBase2 + c];
      xv0 = *(const uint4*)&Xb[xBase + c];
      xv1 = *(const uint4*)&Xb[xBase2 + c];
    }
    // (C) compute from buf[cur]
    bf16x8 bfr[2];
    #pragma unroll
    for (int sf = 0; sf < 2; ++sf)
      bfr[sf] = *(const bf16x8*)&Xt[cur][(wave * 32 + sf * 16 + l16) * 40 + quad * 8];
    #pragma unroll
    for (int of = 0; of < 8; ++of) {
      const bf16x8 afr = *(const bf16x8*)&Wt[cur][(of * 16 + l16) * 40 + quad * 8];
      acc[of][0] = __builtin_amdgcn_mfma_f32_16x16x32_bf16(afr, bfr[0], acc[of][0], 0, 0, 0);
      acc[of][1] = __builtin_amdgcn_mfma_f32_16x16x32_bf16(afr, bfr[1], acc[of][1], 0, 0, 0);
    }
    // (D) one barrier per step
    __syncthreads();
  }

  // epilogue: lane holds D[o = of*16 + quad*4 + r][s = wave*32 + sf*16 + l16]
  if (outMode == 0) {
    ushort* ob = (ushort*)out;
    #pragma unroll
    for (int of = 0; of < 8; ++of) {
      #pragma unroll
      for (int sf = 0; sf < 2; ++sf) {
        const int s = s0 + wave * 32 + sf * 16 + l16;
        const int ol = of * 16 + quad * 4;
        float v0 = acc[of][sf].x + biasS[ol + 0];
        float v1 = acc[of][sf].y + biasS[ol + 1];
        float v2 = acc[of][sf].z + biasS[ol + 2];
        float v3 = acc[of][sf].w + biasS[ol + 3];
        if (relu) {
          v0 = fmaxf(v0, 0.f); v1 = fmaxf(v1, 0.f);
          v2 = fmaxf(v2, 0.f); v3 = fmaxf(v3, 0.f);
        }
        ushort4 st;
        st.x = f2bf(v0); st.y = f2bf(v1); st.z = f2bf(v2); st.w = f2bf(v3);
        *(ushort4*)&ob[((size_t)b * S + s) * ldOut + colOff + o0 + ol] = st;
      }
    }
  } else {
    float* o32 = (float*)out;
    #pragma unroll
    for (int of = 0; of < 8; ++of) {
      #pragma unroll
      for (int sf = 0; sf < 2; ++sf) {
        const int s = s0 + wave * 32 + sf * 16 + l16;
        const int ol = of * 16 + quad * 4;
        const float vr[4] = {acc[of][sf].x, acc[of][sf].y, acc[of][sf].z, acc[of][sf].w};
        #pragma unroll
        for (int r = 0; r < 4; ++r) {
          const int o = o0 + ol + r;
          o32[((size_t)b * O + o) * S + s] = vr[r] + biasS[ol + r];
        }
      }
    }
  }
}

}  // namespace

extern "C" void kernel_launch(void* const* d_in, const int* in_sizes, int n_in,
                              void* d_out, int out_size, void* d_ws, size_t ws_size,
                              hipStream_t stream) {
  const float* seed_xyz  = (const float*)d_in[0];   // [B,S,3]
  const float* p_last    = (const float*)d_in[1];   // [B,M,3]
  const float* f_last    = (const float*)d_in[2];   // [B,C,M]
  const float* seed_feat = (const float*)d_in[3];   // [B,D,S]
  const float* ln_gamma  = (const float*)d_in[4];   // [C]
  const float* ln_beta   = (const float*)d_in[5];   // [C]
  const float* proj_w    = (const float*)d_in[6];   // [D,C]
  const float* proj_b    = (const float*)d_in[7];   // [D]
  const float* mlp_w1    = (const float*)d_in[8];   // [512,512]
  const float* mlp_b1    = (const float*)d_in[9];   // [512]
  const float* mlp_w2    = (const float*)d_in[10];  // [256,512]
  const float* mlp_b2    = (const float*)d_in[11];  // [256]
  float* out = (float*)d_out;                       // [B,256,S] fp32

  // workspace layout:
  //   0      +64KB   idx [B*S] int
  //   64KB   +64KB   sortedIdx
  //   128KB  +64KB   sortedS
  //   256KB  +384KB  proj_w bf16 [256][768]
  //   640KB  +512KB  mlp_w1 bf16 [512][512]
  //   1152KB +256KB  mlp_w2 bf16 [256][512]
  //   2MB    +24MB   xln   bf16 [B][S][768]
  //   26MB   +16MB   fused bf16 [B][S][512]  (0:256 seed_feat^T, 256:512 proj)
  //   42MB   +16MB   h     bf16 [B][S][512]
  char* ws = (char*)d_ws;
  int*    idx   = (int*)(ws);
  int*    sIdx  = (int*)(ws + (64 << 10));
  int*    sS    = (int*)(ws + (128 << 10));
  ushort* wp_bf = (ushort*)(ws + (256 << 10));
  ushort* w1_bf = (ushort*)(ws + (640 << 10));
  ushort* w2_bf = (ushort*)(ws + (1152 << 10));
  ushort* xln   = (ushort*)(ws + (2ull << 20));
  ushort* fused = (ushort*)(ws + (26ull << 20));
  ushort* hbuf  = (ushort*)(ws + (42ull << 20));

  // 1) nearest neighbor + bucket sort by idx
  nn_kernel<<<dim3(S / 64, B), 256, 0, stream>>>(seed_xyz, p_last, idx);
  bucket_sort_kernel<<<dim3(B), 256, 0, stream>>>(idx, sIdx, sS);

  // 2) gather + layernorm -> xln bf16 [B][S][768]  (4 ranks per block)
  gather_ln_kernel<<<dim3(S / 4, B), 256, 0, stream>>>(f_last, sIdx, sS,
                                                       ln_gamma, ln_beta, xln);

  // 3) seed_features -> fused[:, :, 0:256] bf16 ; weights -> bf16 (one kernel)
  prep_kernel<<<dim3(1024 + 768), 256, 0, stream>>>(
      seed_feat, fused,
      proj_w, D * C, wp_bf, mlp_w1, 512 * 512, w1_bf, mlp_w2, 256 * 512, w2_bf);

  // 4) proj = relu(proj_w @ xln + b) -> fused[:, :, 256:512]
  gemm_bf16_kernel<<<dim3(S / 128, 256 / 128, B), 256, 0, stream>>>(
      wp_bf, C, 256, xln, proj_b, fused, 0, 512, 256, 1);

  // 5) h = relu(mlp_w1 @ fused + b1) -> hbuf [B][S][512]
  gemm_bf16_kernel<<<dim3(S / 128, 512 / 128, B), 256, 0, stream>>>(
      w1_bf, 512, 512, fused, mlp_b1, hbuf, 0, 512, 0, 1);

  // 6) out = mlp_w2 @ h + b2 -> fp32 [B][256][S]
  gemm_bf16_kernel<<<dim3(S / 128, 256 / 128, B), 256, 0, stream>>>(
      w2_bf, 512, 256, hbuf, mlp_b2, out, 1, 0, 0, 0);
}

// Round 6
// 407.083 us; speedup vs baseline: 1.1853x; 1.0198x over previous
//
#include <hip/hip_runtime.h>

namespace {

constexpr int B = 16, S = 1024, M = 4096, C = 768, D = 256;

typedef __attribute__((ext_vector_type(8))) short bf16x8;
typedef __attribute__((ext_vector_type(4))) float f32x4;

__device__ inline ushort f2bf(float f) {
  uint u = __float_as_uint(f);
  uint r = (u + 0x7FFFu + ((u >> 16) & 1u)) >> 16;
  return (ushort)r;
}

// ---------------------------------------------------------------------------
// Kernel 1: nearest-neighbor argmin (bit-exact reference distance formula).
// Round-3 verified version: float4 LDS staging, 16 seeds/block.
// ---------------------------------------------------------------------------
__global__ __launch_bounds__(256)
void nn_kernel(const float* __restrict__ xyz, const float* __restrict__ p,
               int* __restrict__ idx_out) {
  const int b = blockIdx.y;
  const int t = threadIdx.x;
  const int seed = blockIdx.x * 16 + (t >> 4);
  const int l16 = t & 15;

  const float sx = xyz[((size_t)b * S + seed) * 3 + 0];
  const float sy = xyz[((size_t)b * S + seed) * 3 + 1];
  const float sz = xyz[((size_t)b * S + seed) * 3 + 2];
  const float ss = __fadd_rn(__fadd_rn(__fmul_rn(sx, sx), __fmul_rn(sy, sy)),
                             __fmul_rn(sz, sz));

  __shared__ float4 pt[256];

  float best = 3.4028235e38f;
  int besti = 0;
  const float* pb = p + (size_t)b * M * 3;

  for (int m0 = 0; m0 < M; m0 += 256) {
    __syncthreads();
    {
      const float a0 = pb[(size_t)(m0 + t) * 3 + 0];
      const float a1 = pb[(size_t)(m0 + t) * 3 + 1];
      const float a2 = pb[(size_t)(m0 + t) * 3 + 2];
      const float pp = __fadd_rn(__fadd_rn(__fmul_rn(a0, a0), __fmul_rn(a1, a1)),
                                 __fmul_rn(a2, a2));
      pt[t] = make_float4(a0, a1, a2, pp);
    }
    __syncthreads();
    #pragma unroll 4
    for (int j = l16; j < 256; j += 16) {
      const float4 q = pt[j];
      float dot = __fmul_rn(sx, q.x);
      dot = __fadd_rn(dot, __fmul_rn(sy, q.y));
      dot = __fadd_rn(dot, __fmul_rn(sz, q.z));
      const float d2 = __fadd_rn(__fsub_rn(ss, __fmul_rn(2.0f, dot)), q.w);
      const int mi = m0 + j;
      if (d2 < best || (d2 == best && mi < besti)) { best = d2; besti = mi; }
    }
  }
  #pragma unroll
  for (int off = 8; off >= 1; off >>= 1) {
    const float ob = __shfl_xor(best, off, 16);
    const int   oi = __shfl_xor(besti, off, 16);
    if (ob < best || (ob == best && oi < besti)) { best = ob; besti = oi; }
  }
  if (l16 == 0) idx_out[b * S + seed] = besti;
}

// ---------------------------------------------------------------------------
// Kernel 1b+3 (merged flat grid):
//   bid <  16           : per-batch counting sort by bucket (m>>4)
//   16 <= bid < 1040    : transpose+convert seed_features -> fused[...,0:256]
//   bid >= 1040         : convert the three weight matrices f32 -> bf16
// Sort wastes 240 CUs for ~3us when launched alone; here its latency hides
// under the independent HBM-streaming prep work (and one launch gap is saved).
// ---------------------------------------------------------------------------
__global__ __launch_bounds__(256)
void sort_prep_kernel(const int* __restrict__ idx, int* __restrict__ sIdx,
                      int* __restrict__ sS,
                      const float* __restrict__ sf, ushort* __restrict__ fused,
                      const float* __restrict__ w0, int n0, ushort* __restrict__ o0,
                      const float* __restrict__ w1, int n1, ushort* __restrict__ o1,
                      const float* __restrict__ w2, int n2, ushort* __restrict__ o2) {
  __shared__ int keys[1024];
  __shared__ int cnt[256];
  __shared__ int base[256];
  __shared__ int wsum[4];
  __shared__ float tile[64][68];

  const int bid = blockIdx.x;
  const int t = threadIdx.x;

  if (bid < 16) {
    const int b = bid;
    cnt[t] = 0;
    #pragma unroll
    for (int i = 0; i < 4; ++i) keys[t + 256 * i] = idx[b * S + t + 256 * i];
    __syncthreads();
    #pragma unroll
    for (int i = 0; i < 4; ++i) atomicAdd(&cnt[keys[t + 256 * i] >> 4], 1);
    __syncthreads();

    const int v = cnt[t];
    int sc = v;
    #pragma unroll
    for (int off = 1; off < 64; off <<= 1) {
      const int o = __shfl_up(sc, off);
      if ((t & 63) >= off) sc += o;
    }
    if ((t & 63) == 63) wsum[t >> 6] = sc;
    __syncthreads();
    int wb = 0;
    #pragma unroll
    for (int w = 0; w < 4; ++w)
      if (w < (t >> 6)) wb += wsum[w];
    base[t] = wb + sc - v;   // exclusive prefix over all 256 buckets
    cnt[t] = 0;              // reuse as intra-bucket offset counter
    __syncthreads();

    #pragma unroll
    for (int i = 0; i < 4; ++i) {
      const int s = t + 256 * i;
      const int m = keys[s];
      const int bu = m >> 4;
      const int r = base[bu] + atomicAdd(&cnt[bu], 1);
      sIdx[b * S + r] = m;
      sS[b * S + r] = s;
    }
  } else if (bid < 16 + 1024) {
    const int pb_ = bid - 16;
    const int b  = pb_ >> 6;
    const int d0 = ((pb_ >> 4) & 3) * 64;
    const int s0 = (pb_ & 15) * 64;

    const float* inb = sf + ((size_t)b * D + d0) * S + s0;
    #pragma unroll
    for (int q = 0; q < 4; ++q) {
      const int rr = (t >> 4) + q * 16;
      const int c4 = (t & 15) * 4;
      const float4 v = *(const float4*)&inb[(size_t)rr * S + c4];
      *(float4*)&tile[rr][c4] = v;
    }
    __syncthreads();
    #pragma unroll
    for (int q = 0; q < 4; ++q) {
      const int srow = (t >> 4) + q * 16;
      const int dc = (t & 15) * 4;
      ushort4 o;
      o.x = f2bf(tile[dc + 0][srow]);
      o.y = f2bf(tile[dc + 1][srow]);
      o.z = f2bf(tile[dc + 2][srow]);
      o.w = f2bf(tile[dc + 3][srow]);
      *(ushort4*)&fused[((size_t)b * S + s0 + srow) * 512 + d0 + dc] = o;
    }
  } else {
    const int id = bid - (16 + 1024);   // 0..767
    const int which = id >> 8;
    const float* src = which == 0 ? w0 : which == 1 ? w1 : w2;
    ushort* dst = which == 0 ? o0 : which == 1 ? o1 : o2;
    const int n = which == 0 ? n0 : which == 1 ? n1 : n2;
    const int i = ((id & 255) * 256 + t) * 4;
    if (i < n) {
      const float4 v = *(const float4*)&src[i];
      ushort4 o;
      o.x = f2bf(v.x); o.y = f2bf(v.y); o.z = f2bf(v.z); o.w = f2bf(v.w);
      *(ushort4*)&dst[i] = o;
    }
  }
}

// ---------------------------------------------------------------------------
// Kernel 2: gather + LayerNorm, FOUR consecutive sorted ranks per block.
// Consecutive ranks share the same m-bucket (= same 64B line per channel),
// so ranks 2..4 hit L1; 12 independent loads in flight per thread.
// XCD-aware swizzle over rank-quads. Output bf16 [B][S][C].
// ---------------------------------------------------------------------------
__global__ __launch_bounds__(256)
void gather_ln_kernel(const float* __restrict__ f, const int* __restrict__ sIdx,
                      const int* __restrict__ sS,
                      const float* __restrict__ gamma, const float* __restrict__ beta,
                      ushort* __restrict__ xln) {
  const int b = blockIdx.y;
  const int rl = blockIdx.x;                         // 0..255
  const int r0 = (((rl & 7) << 5) + (rl >> 3)) << 2; // XCD-contiguous quad rank
  const int t = threadIdx.x;

  int sR[4], mR[4];
  #pragma unroll
  for (int i = 0; i < 4; ++i) {
    sR[i] = sS[b * S + r0 + i];
    mR[i] = sIdx[b * S + r0 + i];
  }

  const float* fb = f + (size_t)b * C * M;
  float v[4][3];
  #pragma unroll
  for (int i = 0; i < 4; ++i) {
    v[i][0] = fb[(size_t)(t      ) * M + mR[i]];
    v[i][1] = fb[(size_t)(t + 256) * M + mR[i]];
    v[i][2] = fb[(size_t)(t + 512) * M + mR[i]];
  }

  const float g0 = gamma[t], g1 = gamma[t + 256], g2 = gamma[t + 512];
  const float e0 = beta[t],  e1 = beta[t + 256],  e2 = beta[t + 512];

  __shared__ float red[4][4];   // [rank][wave]
  __shared__ float stats[8];    // 0..3 mu, 4..7 rsigma
  const int wave = t >> 6;

  float ps[4];
  #pragma unroll
  for (int i = 0; i < 4; ++i) ps[i] = v[i][0] + v[i][1] + v[i][2];
  #pragma unroll
  for (int off = 32; off >= 1; off >>= 1) {
    #pragma unroll
    for (int i = 0; i < 4; ++i) ps[i] += __shfl_xor(ps[i], off);
  }
  if ((t & 63) == 0) {
    #pragma unroll
    for (int i = 0; i < 4; ++i) red[i][wave] = ps[i];
  }
  __syncthreads();
  if (t < 4)
    stats[t] = (red[t][0] + red[t][1] + red[t][2] + red[t][3]) * (1.0f / 768.0f);
  __syncthreads();

  float d[4][3];
  #pragma unroll
  for (int i = 0; i < 4; ++i) {
    const float mu = stats[i];
    d[i][0] = v[i][0] - mu; d[i][1] = v[i][1] - mu; d[i][2] = v[i][2] - mu;
  }
  float pv[4];
  #pragma unroll
  for (int i = 0; i < 4; ++i)
    pv[i] = d[i][0] * d[i][0] + d[i][1] * d[i][1] + d[i][2] * d[i][2];
  #pragma unroll
  for (int off = 32; off >= 1; off >>= 1) {
    #pragma unroll
    for (int i = 0; i < 4; ++i) pv[i] += __shfl_xor(pv[i], off);
  }
  if ((t & 63) == 0) {
    #pragma unroll
    for (int i = 0; i < 4; ++i) red[i][wave] = pv[i];
  }
  __syncthreads();
  if (t < 4) {
    const float var = (red[t][0] + red[t][1] + red[t][2] + red[t][3]) * (1.0f / 768.0f);
    stats[4 + t] = 1.0f / sqrtf(var + 1e-5f);
  }
  __syncthreads();

  #pragma unroll
  for (int i = 0; i < 4; ++i) {
    const float rs = stats[4 + i];
    ushort* o = xln + ((size_t)b * S + sR[i]) * C;
    o[t      ] = f2bf((d[i][0] * rs) * g0 + e0);
    o[t + 256] = f2bf((d[i][1] * rs) * g1 + e1);
    o[t + 512] = f2bf((d[i][2] * rs) * g2 + e2);
  }
}

// ---------------------------------------------------------------------------
// Kernel 5: bf16 MFMA GEMM (Round-3 verified structure).
// out[b,o,s] = act( sum_k W[o,k] X[b,s,k] + bias[o] )
// W: bf16 [O][K] (k contiguous).  X: bf16 [B][S][K] (k contiguous).
// Block: 256 thr (4 waves), tile 128o x 128s; wave w: s-range [w*32, w*32+32).
// Double-buffered LDS, ONE barrier per K-step, 2-step global prefetch.
// outMode 0: bf16 [B][S][ldOut] at column colOff (+optional ReLU)
// outMode 1: fp32 [B][O][S] (final output)
// ---------------------------------------------------------------------------
__global__ __launch_bounds__(256)
void gemm_bf16_kernel(const ushort* __restrict__ W, int K, int O,
                      const ushort* __restrict__ X,
                      const float* __restrict__ bias,
                      void* __restrict__ out, int outMode, int ldOut, int colOff,
                      int relu) {
  const int b  = blockIdx.z;
  const int s0 = blockIdx.x * 128;
  const int o0 = blockIdx.y * 128;
  const int t  = threadIdx.x;
  const int wave = t >> 6;
  const int lane = t & 63;
  const int l16 = lane & 15;
  const int quad = lane >> 4;

  // 80-byte row stride (40 ushorts): 16B-aligned rows, 2-way bank alias (free)
  __shared__ ushort Wt[2][128 * 40];
  __shared__ ushort Xt[2][128 * 40];
  __shared__ float biasS[128];

  if (t < 128) biasS[t] = bias[o0 + t];

  f32x4 acc[8][2];
  const f32x4 z = {0.f, 0.f, 0.f, 0.f};
  #pragma unroll
  for (int of = 0; of < 8; ++of) { acc[of][0] = z; acc[of][1] = z; }

  const ushort* Xb = X + (size_t)b * S * K;
  const int kg = t & 3;        // k-group: 8 bf16 each
  const int row = t >> 2;      // 0..63
  const size_t wBase = (size_t)(o0 + row) * K + kg * 8;
  const size_t xBase = (size_t)(s0 + row) * K + kg * 8;
  const size_t wBase2 = wBase + (size_t)64 * K;
  const size_t xBase2 = xBase + (size_t)64 * K;
  const int T = K >> 5;        // K/32 tiles

  // prologue: tile 0 -> LDS buf0; tile 1 -> regs
  uint4 wv0 = *(const uint4*)&W[wBase];
  uint4 wv1 = *(const uint4*)&W[wBase2];
  uint4 xv0 = *(const uint4*)&Xb[xBase];
  uint4 xv1 = *(const uint4*)&Xb[xBase2];
  *(uint4*)&Wt[0][row * 40 + kg * 8] = wv0;
  *(uint4*)&Wt[0][(row + 64) * 40 + kg * 8] = wv1;
  *(uint4*)&Xt[0][row * 40 + kg * 8] = xv0;
  *(uint4*)&Xt[0][(row + 64) * 40 + kg * 8] = xv1;
  if (T > 1) {
    wv0 = *(const uint4*)&W[wBase + 32];
    wv1 = *(const uint4*)&W[wBase2 + 32];
    xv0 = *(const uint4*)&Xb[xBase + 32];
    xv1 = *(const uint4*)&Xb[xBase2 + 32];
  }
  __syncthreads();   // buf0 visible

  for (int tt = 0; tt < T; ++tt) {
    const int cur = tt & 1;

    // (A) stage tile tt+1 (in regs) into the other buffer
    if (tt + 1 < T) {
      *(uint4*)&Wt[cur ^ 1][row * 40 + kg * 8] = wv0;
      *(uint4*)&Wt[cur ^ 1][(row + 64) * 40 + kg * 8] = wv1;
      *(uint4*)&Xt[cur ^ 1][row * 40 + kg * 8] = xv0;
      *(uint4*)&Xt[cur ^ 1][(row + 64) * 40 + kg * 8] = xv1;
    }
    // (B) issue tile tt+2 global loads
    if (tt + 2 < T) {
      const int c = (tt + 2) * 32;
      wv0 = *(const uint4*)&W[wBase + c];
      wv1 = *(const uint4*)&W[wBase2 + c];
      xv0 = *(const uint4*)&Xb[xBase + c];
      xv1 = *(const uint4*)&Xb[xBase2 + c];
    }
    // (C) compute from buf[cur]
    bf16x8 bfr[2];
    #pragma unroll
    for (int sf = 0; sf < 2; ++sf)
      bfr[sf] = *(const bf16x8*)&Xt[cur][(wave * 32 + sf * 16 + l16) * 40 + quad * 8];
    #pragma unroll
    for (int of = 0; of < 8; ++of) {
      const bf16x8 afr = *(const bf16x8*)&Wt[cur][(of * 16 + l16) * 40 + quad * 8];
      acc[of][0] = __builtin_amdgcn_mfma_f32_16x16x32_bf16(afr, bfr[0], acc[of][0], 0, 0, 0);
      acc[of][1] = __builtin_amdgcn_mfma_f32_16x16x32_bf16(afr, bfr[1], acc[of][1], 0, 0, 0);
    }
    // (D) one barrier per step
    __syncthreads();
  }

  // epilogue: lane holds D[o = of*16 + quad*4 + r][s = wave*32 + sf*16 + l16]
  if (outMode == 0) {
    ushort* ob = (ushort*)out;
    #pragma unroll
    for (int of = 0; of < 8; ++of) {
      #pragma unroll
      for (int sf = 0; sf < 2; ++sf) {
        const int s = s0 + wave * 32 + sf * 16 + l16;
        const int ol = of * 16 + quad * 4;
        float v0 = acc[of][sf].x + biasS[ol + 0];
        float v1 = acc[of][sf].y + biasS[ol + 1];
        float v2 = acc[of][sf].z + biasS[ol + 2];
        float v3 = acc[of][sf].w + biasS[ol + 3];
        if (relu) {
          v0 = fmaxf(v0, 0.f); v1 = fmaxf(v1, 0.f);
          v2 = fmaxf(v2, 0.f); v3 = fmaxf(v3, 0.f);
        }
        ushort4 st;
        st.x = f2bf(v0); st.y = f2bf(v1); st.z = f2bf(v2); st.w = f2bf(v3);
        *(ushort4*)&ob[((size_t)b * S + s) * ldOut + colOff + o0 + ol] = st;
      }
    }
  } else {
    float* o32 = (float*)out;
    #pragma unroll
    for (int of = 0; of < 8; ++of) {
      #pragma unroll
      for (int sf = 0; sf < 2; ++sf) {
        const int s = s0 + wave * 32 + sf * 16 + l16;
        const int ol = of * 16 + quad * 4;
        const float vr[4] = {acc[of][sf].x, acc[of][sf].y, acc[of][sf].z, acc[of][sf].w};
        #pragma unroll
        for (int r = 0; r < 4; ++r) {
          const int o = o0 + ol + r;
          o32[((size_t)b * O + o) * S + s] = vr[r] + biasS[ol + r];
        }
      }
    }
  }
}

}  // namespace

extern "C" void kernel_launch(void* const* d_in, const int* in_sizes, int n_in,
                              void* d_out, int out_size, void* d_ws, size_t ws_size,
                              hipStream_t stream) {
  const float* seed_xyz  = (const float*)d_in[0];   // [B,S,3]
  const float* p_last    = (const float*)d_in[1];   // [B,M,3]
  const float* f_last    = (const float*)d_in[2];   // [B,C,M]
  const float* seed_feat = (const float*)d_in[3];   // [B,D,S]
  const float* ln_gamma  = (const float*)d_in[4];   // [C]
  const float* ln_beta   = (const float*)d_in[5];   // [C]
  const float* proj_w    = (const float*)d_in[6];   // [D,C]
  const float* proj_b    = (const float*)d_in[7];   // [D]
  const float* mlp_w1    = (const float*)d_in[8];   // [512,512]
  const float* mlp_b1    = (const float*)d_in[9];   // [512]
  const float* mlp_w2    = (const float*)d_in[10];  // [256,512]
  const float* mlp_b2    = (const float*)d_in[11];  // [256]
  float* out = (float*)d_out;                       // [B,256,S] fp32

  // workspace layout:
  //   0      +64KB   idx [B*S] int
  //   64KB   +64KB   sortedIdx
  //   128KB  +64KB   sortedS
  //   256KB  +384KB  proj_w bf16 [256][768]
  //   640KB  +512KB  mlp_w1 bf16 [512][512]
  //   1152KB +256KB  mlp_w2 bf16 [256][512]
  //   2MB    +24MB   xln   bf16 [B][S][768]
  //   26MB   +16MB   fused bf16 [B][S][512]  (0:256 seed_feat^T, 256:512 proj)
  //   42MB   +16MB   h     bf16 [B][S][512]
  char* ws = (char*)d_ws;
  int*    idx   = (int*)(ws);
  int*    sIdx  = (int*)(ws + (64 << 10));
  int*    sS    = (int*)(ws + (128 << 10));
  ushort* wp_bf = (ushort*)(ws + (256 << 10));
  ushort* w1_bf = (ushort*)(ws + (640 << 10));
  ushort* w2_bf = (ushort*)(ws + (1152 << 10));
  ushort* xln   = (ushort*)(ws + (2ull << 20));
  ushort* fused = (ushort*)(ws + (26ull << 20));
  ushort* hbuf  = (ushort*)(ws + (42ull << 20));

  // 1) nearest neighbor
  nn_kernel<<<dim3(S / 16, B), 256, 0, stream>>>(seed_xyz, p_last, idx);

  // 2) bucket sort + seed_features transpose + weight convert (one kernel)
  sort_prep_kernel<<<dim3(16 + 1024 + 768), 256, 0, stream>>>(
      idx, sIdx, sS, seed_feat, fused,
      proj_w, D * C, wp_bf, mlp_w1, 512 * 512, w1_bf, mlp_w2, 256 * 512, w2_bf);

  // 3) gather + layernorm -> xln bf16 [B][S][768]  (4 ranks per block)
  gather_ln_kernel<<<dim3(S / 4, B), 256, 0, stream>>>(f_last, sIdx, sS,
                                                       ln_gamma, ln_beta, xln);

  // 4) proj = relu(proj_w @ xln + b) -> fused[:, :, 256:512]
  gemm_bf16_kernel<<<dim3(S / 128, 256 / 128, B), 256, 0, stream>>>(
      wp_bf, C, 256, xln, proj_b, fused, 0, 512, 256, 1);

  // 5) h = relu(mlp_w1 @ fused + b1) -> hbuf [B][S][512]
  gemm_bf16_kernel<<<dim3(S / 128, 512 / 128, B), 256, 0, stream>>>(
      w1_bf, 512, 512, fused, mlp_b1, hbuf, 0, 512, 0, 1);

  // 6) out = mlp_w2 @ h + b2 -> fp32 [B][256][S]
  gemm_bf16_kernel<<<dim3(S / 128, 256 / 128, B), 256, 0, stream>>>(
      w2_bf, 512, 256, hbuf, mlp_b2, out, 1, 0, 0, 0);
}

// Round 9
// 406.715 us; speedup vs baseline: 1.1864x; 1.0009x over previous
//
#include <hip/hip_runtime.h>

namespace {

constexpr int B = 16, S = 1024, M = 4096, C = 768, D = 256;

typedef __attribute__((ext_vector_type(8))) short bf16x8;
typedef __attribute__((ext_vector_type(4))) float f32x4;

__device__ inline ushort f2bf(float f) {
  uint u = __float_as_uint(f);
  uint r = (u + 0x7FFFu + ((u >> 16) & 1u)) >> 16;
  return (ushort)r;
}

// ---------------------------------------------------------------------------
// Kernel 1: nearest-neighbor argmin (bit-exact reference distance formula).
// Round-3 verified version: float4 LDS staging, 16 seeds/block.
// ---------------------------------------------------------------------------
__global__ __launch_bounds__(256)
void nn_kernel(const float* __restrict__ xyz, const float* __restrict__ p,
               int* __restrict__ idx_out) {
  const int b = blockIdx.y;
  const int t = threadIdx.x;
  const int seed = blockIdx.x * 16 + (t >> 4);
  const int l16 = t & 15;

  const float sx = xyz[((size_t)b * S + seed) * 3 + 0];
  const float sy = xyz[((size_t)b * S + seed) * 3 + 1];
  const float sz = xyz[((size_t)b * S + seed) * 3 + 2];
  const float ss = __fadd_rn(__fadd_rn(__fmul_rn(sx, sx), __fmul_rn(sy, sy)),
                             __fmul_rn(sz, sz));

  __shared__ float4 pt[256];

  float best = 3.4028235e38f;
  int besti = 0;
  const float* pb = p + (size_t)b * M * 3;

  for (int m0 = 0; m0 < M; m0 += 256) {
    __syncthreads();
    {
      const float a0 = pb[(size_t)(m0 + t) * 3 + 0];
      const float a1 = pb[(size_t)(m0 + t) * 3 + 1];
      const float a2 = pb[(size_t)(m0 + t) * 3 + 2];
      const float pp = __fadd_rn(__fadd_rn(__fmul_rn(a0, a0), __fmul_rn(a1, a1)),
                                 __fmul_rn(a2, a2));
      pt[t] = make_float4(a0, a1, a2, pp);
    }
    __syncthreads();
    #pragma unroll 4
    for (int j = l16; j < 256; j += 16) {
      const float4 q = pt[j];
      float dot = __fmul_rn(sx, q.x);
      dot = __fadd_rn(dot, __fmul_rn(sy, q.y));
      dot = __fadd_rn(dot, __fmul_rn(sz, q.z));
      const float d2 = __fadd_rn(__fsub_rn(ss, __fmul_rn(2.0f, dot)), q.w);
      const int mi = m0 + j;
      if (d2 < best || (d2 == best && mi < besti)) { best = d2; besti = mi; }
    }
  }
  #pragma unroll
  for (int off = 8; off >= 1; off >>= 1) {
    const float ob = __shfl_xor(best, off, 16);
    const int   oi = __shfl_xor(besti, off, 16);
    if (ob < best || (ob == best && oi < besti)) { best = ob; besti = oi; }
  }
  if (l16 == 0) idx_out[b * S + seed] = besti;
}

// ---------------------------------------------------------------------------
// Kernel 1b+3 (merged flat grid):
//   bid <  16           : per-batch counting sort by bucket (m>>4)
//   16 <= bid < 1040    : transpose+convert seed_features -> fused[...,0:256]
//   bid >= 1040         : convert the three weight matrices f32 -> bf16
// ---------------------------------------------------------------------------
__global__ __launch_bounds__(256)
void sort_prep_kernel(const int* __restrict__ idx, int* __restrict__ sIdx,
                      int* __restrict__ sS,
                      const float* __restrict__ sf, ushort* __restrict__ fused,
                      const float* __restrict__ w0, int n0, ushort* __restrict__ o0,
                      const float* __restrict__ w1, int n1, ushort* __restrict__ o1,
                      const float* __restrict__ w2, int n2, ushort* __restrict__ o2) {
  __shared__ int keys[1024];
  __shared__ int cnt[256];
  __shared__ int base[256];
  __shared__ int wsum[4];
  __shared__ float tile[64][68];

  const int bid = blockIdx.x;
  const int t = threadIdx.x;

  if (bid < 16) {
    const int b = bid;
    cnt[t] = 0;
    #pragma unroll
    for (int i = 0; i < 4; ++i) keys[t + 256 * i] = idx[b * S + t + 256 * i];
    __syncthreads();
    #pragma unroll
    for (int i = 0; i < 4; ++i) atomicAdd(&cnt[keys[t + 256 * i] >> 4], 1);
    __syncthreads();

    const int v = cnt[t];
    int sc = v;
    #pragma unroll
    for (int off = 1; off < 64; off <<= 1) {
      const int o = __shfl_up(sc, off);
      if ((t & 63) >= off) sc += o;
    }
    if ((t & 63) == 63) wsum[t >> 6] = sc;
    __syncthreads();
    int wb = 0;
    #pragma unroll
    for (int w = 0; w < 4; ++w)
      if (w < (t >> 6)) wb += wsum[w];
    base[t] = wb + sc - v;   // exclusive prefix over all 256 buckets
    cnt[t] = 0;              // reuse as intra-bucket offset counter
    __syncthreads();

    #pragma unroll
    for (int i = 0; i < 4; ++i) {
      const int s = t + 256 * i;
      const int m = keys[s];
      const int bu = m >> 4;
      const int r = base[bu] + atomicAdd(&cnt[bu], 1);
      sIdx[b * S + r] = m;
      sS[b * S + r] = s;
    }
  } else if (bid < 16 + 1024) {
    const int pb_ = bid - 16;
    const int b  = pb_ >> 6;
    const int d0 = ((pb_ >> 4) & 3) * 64;
    const int s0 = (pb_ & 15) * 64;

    const float* inb = sf + ((size_t)b * D + d0) * S + s0;
    #pragma unroll
    for (int q = 0; q < 4; ++q) {
      const int rr = (t >> 4) + q * 16;
      const int c4 = (t & 15) * 4;
      const float4 v = *(const float4*)&inb[(size_t)rr * S + c4];
      *(float4*)&tile[rr][c4] = v;
    }
    __syncthreads();
    #pragma unroll
    for (int q = 0; q < 4; ++q) {
      const int srow = (t >> 4) + q * 16;
      const int dc = (t & 15) * 4;
      ushort4 o;
      o.x = f2bf(tile[dc + 0][srow]);
      o.y = f2bf(tile[dc + 1][srow]);
      o.z = f2bf(tile[dc + 2][srow]);
      o.w = f2bf(tile[dc + 3][srow]);
      *(ushort4*)&fused[((size_t)b * S + s0 + srow) * 512 + d0 + dc] = o;
    }
  } else {
    const int id = bid - (16 + 1024);   // 0..767
    const int which = id >> 8;
    const float* src = which == 0 ? w0 : which == 1 ? w1 : w2;
    ushort* dst = which == 0 ? o0 : which == 1 ? o1 : o2;
    const int n = which == 0 ? n0 : which == 1 ? n1 : n2;
    const int i = ((id & 255) * 256 + t) * 4;
    if (i < n) {
      const float4 v = *(const float4*)&src[i];
      ushort4 o;
      o.x = f2bf(v.x); o.y = f2bf(v.y); o.z = f2bf(v.z); o.w = f2bf(v.w);
      *(ushort4*)&dst[i] = o;
    }
  }
}

// ---------------------------------------------------------------------------
// Kernel 2: gather + LayerNorm, FOUR consecutive sorted ranks per block.
// ---------------------------------------------------------------------------
__global__ __launch_bounds__(256)
void gather_ln_kernel(const float* __restrict__ f, const int* __restrict__ sIdx,
                      const int* __restrict__ sS,
                      const float* __restrict__ gamma, const float* __restrict__ beta,
                      ushort* __restrict__ xln) {
  const int b = blockIdx.y;
  const int rl = blockIdx.x;                         // 0..255
  const int r0 = (((rl & 7) << 5) + (rl >> 3)) << 2; // XCD-contiguous quad rank
  const int t = threadIdx.x;

  int sR[4], mR[4];
  #pragma unroll
  for (int i = 0; i < 4; ++i) {
    sR[i] = sS[b * S + r0 + i];
    mR[i] = sIdx[b * S + r0 + i];
  }

  const float* fb = f + (size_t)b * C * M;
  float v[4][3];
  #pragma unroll
  for (int i = 0; i < 4; ++i) {
    v[i][0] = fb[(size_t)(t      ) * M + mR[i]];
    v[i][1] = fb[(size_t)(t + 256) * M + mR[i]];
    v[i][2] = fb[(size_t)(t + 512) * M + mR[i]];
  }

  const float g0 = gamma[t], g1 = gamma[t + 256], g2 = gamma[t + 512];
  const float e0 = beta[t],  e1 = beta[t + 256],  e2 = beta[t + 512];

  __shared__ float red[4][4];   // [rank][wave]
  __shared__ float stats[8];    // 0..3 mu, 4..7 rsigma
  const int wave = t >> 6;

  float ps[4];
  #pragma unroll
  for (int i = 0; i < 4; ++i) ps[i] = v[i][0] + v[i][1] + v[i][2];
  #pragma unroll
  for (int off = 32; off >= 1; off >>= 1) {
    #pragma unroll
    for (int i = 0; i < 4; ++i) ps[i] += __shfl_xor(ps[i], off);
  }
  if ((t & 63) == 0) {
    #pragma unroll
    for (int i = 0; i < 4; ++i) red[i][wave] = ps[i];
  }
  __syncthreads();
  if (t < 4)
    stats[t] = (red[t][0] + red[t][1] + red[t][2] + red[t][3]) * (1.0f / 768.0f);
  __syncthreads();

  float d[4][3];
  #pragma unroll
  for (int i = 0; i < 4; ++i) {
    const float mu = stats[i];
    d[i][0] = v[i][0] - mu; d[i][1] = v[i][1] - mu; d[i][2] = v[i][2] - mu;
  }
  float pv[4];
  #pragma unroll
  for (int i = 0; i < 4; ++i)
    pv[i] = d[i][0] * d[i][0] + d[i][1] * d[i][1] + d[i][2] * d[i][2];
  #pragma unroll
  for (int off = 32; off >= 1; off >>= 1) {
    #pragma unroll
    for (int i = 0; i < 4; ++i) pv[i] += __shfl_xor(pv[i], off);
  }
  if ((t & 63) == 0) {
    #pragma unroll
    for (int i = 0; i < 4; ++i) red[i][wave] = pv[i];
  }
  __syncthreads();
  if (t < 4) {
    const float var = (red[t][0] + red[t][1] + red[t][2] + red[t][3]) * (1.0f / 768.0f);
    stats[4 + t] = 1.0f / sqrtf(var + 1e-5f);
  }
  __syncthreads();

  #pragma unroll
  for (int i = 0; i < 4; ++i) {
    const float rs = stats[4 + i];
    ushort* o = xln + ((size_t)b * S + sR[i]) * C;
    o[t      ] = f2bf((d[i][0] * rs) * g0 + e0);
    o[t + 256] = f2bf((d[i][1] * rs) * g1 + e1);
    o[t + 512] = f2bf((d[i][2] * rs) * g2 + e2);
  }
}

// ---------------------------------------------------------------------------
// Kernel 5: bf16 MFMA GEMM (Round-3/6 verified structure).
// out[b,o,s] = act( sum_k W[o,k] X[b,s,k] + bias[o] )
// W: bf16 [O][K] (k contiguous).  X: bf16 [B][S][K] (k contiguous).
// Block: 256 thr (4 waves), tile 128o x 128s; wave w: s-range [w*32, w*32+32).
// Double-buffered LDS, ONE barrier per K-step, 2-step global prefetch.
// outMode 0: bf16 [B][S][ldOut] at column colOff (+optional ReLU)
// outMode 1: fp32 [B][O][S] (final output)
// ---------------------------------------------------------------------------
__global__ __launch_bounds__(256)
void gemm_bf16_kernel(const ushort* __restrict__ W, int K, int O,
                      const ushort* __restrict__ X,
                      const float* __restrict__ bias,
                      void* __restrict__ out, int outMode, int ldOut, int colOff,
                      int relu) {
  const int b  = blockIdx.z;
  const int s0 = blockIdx.x * 128;
  const int o0 = blockIdx.y * 128;
  const int t  = threadIdx.x;
  const int wave = t >> 6;
  const int lane = t & 63;
  const int l16 = lane & 15;
  const int quad = lane >> 4;

  // 80-byte row stride (40 ushorts): 16B-aligned rows, 2-way bank alias (free)
  __shared__ ushort Wt[2][128 * 40];
  __shared__ ushort Xt[2][128 * 40];
  __shared__ float biasS[128];

  if (t < 128) biasS[t] = bias[o0 + t];

  f32x4 acc[8][2];
  const f32x4 z = {0.f, 0.f, 0.f, 0.f};
  #pragma unroll
  for (int of = 0; of < 8; ++of) { acc[of][0] = z; acc[of][1] = z; }

  const ushort* Xb = X + (size_t)b * S * K;
  const int kg = t & 3;        // k-group: 8 bf16 each
  const int row = t >> 2;      // 0..63
  const size_t wBase = (size_t)(o0 + row) * K + kg * 8;
  const size_t xBase = (size_t)(s0 + row) * K + kg * 8;
  const size_t wBase2 = wBase + (size_t)64 * K;
  const size_t xBase2 = xBase + (size_t)64 * K;
  const int T = K >> 5;        // K/32 tiles

  // prologue: tile 0 -> LDS buf0; tile 1 -> regs
  uint4 wv0 = *(const uint4*)&W[wBase];
  uint4 wv1 = *(const uint4*)&W[wBase2];
  uint4 xv0 = *(const uint4*)&Xb[xBase];
  uint4 xv1 = *(const uint4*)&Xb[xBase2];
  *(uint4*)&Wt[0][row * 40 + kg * 8] = wv0;
  *(uint4*)&Wt[0][(row + 64) * 40 + kg * 8] = wv1;
  *(uint4*)&Xt[0][row * 40 + kg * 8] = xv0;
  *(uint4*)&Xt[0][(row + 64) * 40 + kg * 8] = xv1;
  if (T > 1) {
    wv0 = *(const uint4*)&W[wBase + 32];
    wv1 = *(const uint4*)&W[wBase2 + 32];
    xv0 = *(const uint4*)&Xb[xBase + 32];
    xv1 = *(const uint4*)&Xb[xBase2 + 32];
  }
  __syncthreads();   // buf0 visible

  for (int tt = 0; tt < T; ++tt) {
    const int cur = tt & 1;

    // (A) stage tile tt+1 (in regs) into the other buffer
    if (tt + 1 < T) {
      *(uint4*)&Wt[cur ^ 1][row * 40 + kg * 8] = wv0;
      *(uint4*)&Wt[cur ^ 1][(row + 64) * 40 + kg * 8] = wv1;
      *(uint4*)&Xt[cur ^ 1][row * 40 + kg * 8] = xv0;
      *(uint4*)&Xt[cur ^ 1][(row + 64) * 40 + kg * 8] = xv1;
    }
    // (B) issue tile tt+2 global loads
    if (tt + 2 < T) {
      const int c = (tt + 2) * 32;
      wv0 = *(const uint4*)&W[wBase + c];
      wv1 = *(const uint4*)&W[wBase2 + c];
      xv0 = *(const uint4*)&Xb[xBase + c];
      xv1 = *(const uint4*)&Xb[xBase2 + c];
    }
    // (C) compute from buf[cur]
    bf16x8 bfr[2];
    #pragma unroll
    for (int sf = 0; sf < 2; ++sf)
      bfr[sf] = *(const bf16x8*)&Xt[cur][(wave * 32 + sf * 16 + l16) * 40 + quad * 8];
    #pragma unroll
    for (int of = 0; of < 8; ++of) {
      const bf16x8 afr = *(const bf16x8*)&Wt[cur][(of * 16 + l16) * 40 + quad * 8];
      acc[of][0] = __builtin_amdgcn_mfma_f32_16x16x32_bf16(afr, bfr[0], acc[of][0], 0, 0, 0);
      acc[of][1] = __builtin_amdgcn_mfma_f32_16x16x32_bf16(afr, bfr[1], acc[of][1], 0, 0, 0);
    }
    // (D) one barrier per step
    __syncthreads();
  }

  // epilogue: lane holds D[o = of*16 + quad*4 + r][s = wave*32 + sf*16 + l16]
  if (outMode == 0) {
    ushort* ob = (ushort*)out;
    #pragma unroll
    for (int of = 0; of < 8; ++of) {
      #pragma unroll
      for (int sf = 0; sf < 2; ++sf) {
        const int s = s0 + wave * 32 + sf * 16 + l16;
        const int ol = of * 16 + quad * 4;
        float v0 = acc[of][sf].x + biasS[ol + 0];
        float v1 = acc[of][sf].y + biasS[ol + 1];
        float v2 = acc[of][sf].z + biasS[ol + 2];
        float v3 = acc[of][sf].w + biasS[ol + 3];
        if (relu) {
          v0 = fmaxf(v0, 0.f); v1 = fmaxf(v1, 0.f);
          v2 = fmaxf(v2, 0.f); v3 = fmaxf(v3, 0.f);
        }
        ushort4 st;
        st.x = f2bf(v0); st.y = f2bf(v1); st.z = f2bf(v2); st.w = f2bf(v3);
        *(ushort4*)&ob[((size_t)b * S + s) * ldOut + colOff + o0 + ol] = st;
      }
    }
  } else {
    float* o32 = (float*)out;
    #pragma unroll
    for (int of = 0; of < 8; ++of) {
      #pragma unroll
      for (int sf = 0; sf < 2; ++sf) {
        const int s = s0 + wave * 32 + sf * 16 + l16;
        const int ol = of * 16 + quad * 4;
        const float vr[4] = {acc[of][sf].x, acc[of][sf].y, acc[of][sf].z, acc[of][sf].w};
        #pragma unroll
        for (int r = 0; r < 4; ++r) {
          const int o = o0 + ol + r;
          o32[((size_t)b * O + o) * S + s] = vr[r] + biasS[ol + r];
        }
      }
    }
  }
}

}  // namespace

extern "C" void kernel_launch(void* const* d_in, const int* in_sizes, int n_in,
                              void* d_out, int out_size, void* d_ws, size_t ws_size,
                              hipStream_t stream) {
  const float* seed_xyz  = (const float*)d_in[0];   // [B,S,3]
  const float* p_last    = (const float*)d_in[1];   // [B,M,3]
  const float* f_last    = (const float*)d_in[2];   // [B,C,M]
  const float* seed_feat = (const float*)d_in[3];   // [B,D,S]
  const float* ln_gamma  = (const float*)d_in[4];   // [C]
  const float* ln_beta   = (const float*)d_in[5];   // [C]
  const float* proj_w    = (const float*)d_in[6];   // [D,C]
  const float* proj_b    = (const float*)d_in[7];   // [D]
  const float* mlp_w1    = (const float*)d_in[8];   // [512,512]
  const float* mlp_b1    = (const float*)d_in[9];   // [512]
  const float* mlp_w2    = (const float*)d_in[10];  // [256,512]
  const float* mlp_b2    = (const float*)d_in[11];  // [256]
  float* out = (float*)d_out;                       // [B,256,S] fp32

  // workspace layout:
  //   0      +64KB   idx [B*S] int
  //   64KB   +64KB   sortedIdx
  //   128KB  +64KB   sortedS
  //   256KB  +384KB  proj_w bf16 [256][768]
  //   640KB  +512KB  mlp_w1 bf16 [512][512]
  //   1152KB +256KB  mlp_w2 bf16 [256][512]
  //   2MB    +24MB   xln   bf16 [B][S][768]
  //   26MB   +16MB   fused bf16 [B][S][512]  (0:256 seed_feat^T, 256:512 proj)
  //   42MB   +16MB   h     bf16 [B][S][512]
  char* ws = (char*)d_ws;
  int*    idx   = (int*)(ws);
  int*    sIdx  = (int*)(ws + (64 << 10));
  int*    sS    = (int*)(ws + (128 << 10));
  ushort* wp_bf = (ushort*)(ws + (256 << 10));
  ushort* w1_bf = (ushort*)(ws + (640 << 10));
  ushort* w2_bf = (ushort*)(ws + (1152 << 10));
  ushort* xln   = (ushort*)(ws + (2ull << 20));
  ushort* fused = (ushort*)(ws + (26ull << 20));
  ushort* hbuf  = (ushort*)(ws + (42ull << 20));

  // 1) nearest neighbor
  nn_kernel<<<dim3(S / 16, B), 256, 0, stream>>>(seed_xyz, p_last, idx);

  // 2) bucket sort + seed_features transpose + weight convert (one kernel)
  sort_prep_kernel<<<dim3(16 + 1024 + 768), 256, 0, stream>>>(
      idx, sIdx, sS, seed_feat, fused,
      proj_w, D * C, wp_bf, mlp_w1, 512 * 512, w1_bf, mlp_w2, 256 * 512, w2_bf);

  // 3) gather + layernorm -> xln bf16 [B][S][768]  (4 ranks per block)
  gather_ln_kernel<<<dim3(S / 4, B), 256, 0, stream>>>(f_last, sIdx, sS,
                                                       ln_gamma, ln_beta, xln);

  // 4) proj = relu(proj_w @ xln + b) -> fused[:, :, 256:512]
  gemm_bf16_kernel<<<dim3(S / 128, 256 / 128, B), 256, 0, stream>>>(
      wp_bf, C, 256, xln, proj_b, fused, 0, 512, 256, 1);

  // 5) h = relu(mlp_w1 @ fused + b1) -> hbuf [B][S][512]
  gemm_bf16_kernel<<<dim3(S / 128, 512 / 128, B), 256, 0, stream>>>(
      w1_bf, 512, 512, fused, mlp_b1, hbuf, 0, 512, 0, 1);

  // 6) out = mlp_w2 @ h + b2 -> fp32 [B][256][S]
  gemm_bf16_kernel<<<dim3(S / 128, 256 / 128, B), 256, 0, stream>>>(
      w2_bf, 512, 256, hbuf, mlp_b2, out, 1, 0, 0, 0);
}